// Round 3
// baseline (385.521 us; speedup 1.0000x reference)
//
#include <hip/hip_runtime.h>

// OnlineReweightingLoss: N=1048576, C=64, S=8.
// out = sum_k ( sum_{i in key k} per_sample_i ) / count_k
//
// Single fused pass: 16 lanes/row (lane owns one float4), 16 rows per
// wave-iter via 4 independent coalesced 1 KB nontemporal dwordx4 loads.
// Row-sum via shfl_xor(width=16); target-owner lane accumulates
// (sum, count) into a 512-bin LDS histogram; block flushes via atomics.
// 2048 blocks = 32 waves/CU (max occupancy) for latency hiding.

#define NKEYS 512
typedef float v4f __attribute__((ext_vector_type(4)));

__device__ __forceinline__ float pick4(v4f v, int j) {
    float r = v.x;
    r = (j == 1) ? v.y : r;
    r = (j == 2) ? v.z : r;
    r = (j == 3) ? v.w : r;
    return r;
}

__device__ __forceinline__ float esum4(v4f v) {
    return __expf(v.x) + __expf(v.y) + __expf(v.z) + __expf(v.w);
}

__global__ __launch_bounds__(256)
void orl_fused_kernel(const float* __restrict__ logits,
                      const int* __restrict__ targets,
                      const int* __restrict__ subg,
                      float* __restrict__ gsum,          // [NKEYS]
                      unsigned int* __restrict__ gcnt,   // [NKEYS]
                      int n) {
    __shared__ float        lsum[NKEYS];
    __shared__ unsigned int lcnt[NKEYS];
    for (int i = threadIdx.x; i < NKEYS; i += 256) { lsum[i] = 0.0f; lcnt[i] = 0u; }
    __syncthreads();

    const int lane = threadIdx.x & 63;
    const int q    = lane & 15;        // float4 index within row
    const int g    = lane >> 4;        // row within 4-row group
    const int wave = (blockIdx.x << 2) | (threadIdx.x >> 6);
    const int nwaves = gridDim.x << 2;

    int base = wave * 16;
    for (; base + 16 <= n; base += nwaves * 16) {
        const int r0 = base + g, r1 = base + 4 + g, r2 = base + 8 + g, r3 = base + 12 + g;
        // 4 independent, fully-coalesced 1 KB loads issued before any use.
        // Nontemporal: logits have zero reuse — don't pollute L1/L2.
        const v4f v0 = __builtin_nontemporal_load((const v4f*)(logits + (size_t)r0 * 64) + q);
        const v4f v1 = __builtin_nontemporal_load((const v4f*)(logits + (size_t)r1 * 64) + q);
        const v4f v2 = __builtin_nontemporal_load((const v4f*)(logits + (size_t)r2 * 64) + q);
        const v4f v3 = __builtin_nontemporal_load((const v4f*)(logits + (size_t)r3 * 64) + q);
        const int t0 = targets[r0], t1 = targets[r1], t2 = targets[r2], t3 = targets[r3];

        float s0 = esum4(v0), s1 = esum4(v1), s2 = esum4(v2), s3 = esum4(v3);
        #pragma unroll
        for (int m = 1; m < 16; m <<= 1) {
            s0 += __shfl_xor(s0, m, 16);
            s1 += __shfl_xor(s1, m, 16);
            s2 += __shfl_xor(s2, m, 16);
            s3 += __shfl_xor(s3, m, 16);
        }
        if ((t0 >> 2) == q) {
            const float ps = __logf(s0) - pick4(v0, t0 & 3);
            const int key = t0 * 8 + subg[r0];
            atomicAdd(&lsum[key], ps); atomicAdd(&lcnt[key], 1u);
        }
        if ((t1 >> 2) == q) {
            const float ps = __logf(s1) - pick4(v1, t1 & 3);
            const int key = t1 * 8 + subg[r1];
            atomicAdd(&lsum[key], ps); atomicAdd(&lcnt[key], 1u);
        }
        if ((t2 >> 2) == q) {
            const float ps = __logf(s2) - pick4(v2, t2 & 3);
            const int key = t2 * 8 + subg[r2];
            atomicAdd(&lsum[key], ps); atomicAdd(&lcnt[key], 1u);
        }
        if ((t3 >> 2) == q) {
            const float ps = __logf(s3) - pick4(v3, t3 & 3);
            const int key = t3 * 8 + subg[r3];
            atomicAdd(&lsum[key], ps); atomicAdd(&lcnt[key], 1u);
        }
    }
    // generic-n tail (never taken for N=1M with this grid, kept for safety)
    for (int o = 0; o < 16; o += 4) {
        const int r = base + o + g;
        if (r < n) {
            const v4f v = *((const v4f*)(logits + (size_t)r * 64) + q);
            const int t = targets[r];
            float s = esum4(v);
            #pragma unroll
            for (int m = 1; m < 16; m <<= 1) s += __shfl_xor(s, m, 16);
            if ((t >> 2) == q) {
                const float ps = __logf(s) - pick4(v, t & 3);
                const int key = t * 8 + subg[r];
                atomicAdd(&lsum[key], ps); atomicAdd(&lcnt[key], 1u);
            }
        }
    }

    __syncthreads();
    for (int i = threadIdx.x; i < NKEYS; i += 256) {
        const unsigned int c = lcnt[i];
        if (c) {
            atomicAdd(&gsum[i], lsum[i]);
            atomicAdd(&gcnt[i], c);
        }
    }
}

__global__ __launch_bounds__(512)
void orl_final_kernel(const float* __restrict__ gsum,
                      const unsigned int* __restrict__ gcnt,
                      float* __restrict__ out) {
    const int k = threadIdx.x;            // one block of 512 threads
    const unsigned int c = gcnt[k];
    float v = c ? gsum[k] / (float)c : 0.0f;
    #pragma unroll
    for (int m = 32; m > 0; m >>= 1) v += __shfl_down(v, m, 64);
    __shared__ float wsum[8];
    if ((k & 63) == 0) wsum[k >> 6] = v;
    __syncthreads();
    if (k == 0) {
        float t = 0.0f;
        #pragma unroll
        for (int w = 0; w < 8; ++w) t += wsum[w];
        out[0] = t;
    }
}

extern "C" void kernel_launch(void* const* d_in, const int* in_sizes, int n_in,
                              void* d_out, int out_size, void* d_ws, size_t ws_size,
                              hipStream_t stream) {
    const float* logits  = (const float*)d_in[0];
    const int*   targets = (const int*)d_in[1];
    const int*   subg    = (const int*)d_in[2];
    const int n = in_sizes[1];
    float* out = (float*)d_out;

    float*        gsum = (float*)d_ws;
    unsigned int* gcnt = (unsigned int*)((char*)d_ws + NKEYS * sizeof(float));

    // ws is poisoned to 0xAA before every call — zero the 4 KB we use.
    hipMemsetAsync(d_ws, 0, NKEYS * (sizeof(float) + sizeof(unsigned int)), stream);

    // 2048 blocks x 4 waves = 8192 waves = 32 waves/CU (max occupancy);
    // 16 rows per wave-iter -> 8 sweeps over N=1M.
    orl_fused_kernel<<<2048, 256, 0, stream>>>(logits, targets, subg, gsum, gcnt, n);
    orl_final_kernel<<<1, 512, 0, stream>>>(gsum, gcnt, out);
}